// Round 1
// baseline (767.122 us; speedup 1.0000x reference)
//
#include <hip/hip_runtime.h>

#define T_TOK 8192
#define DIMSZ 512
#define HIDSZ 1536
#define SHIDSZ 3072
#define NE 8

typedef __attribute__((ext_vector_type(4))) float f32x4;
typedef __attribute__((ext_vector_type(8))) short s16x8;

__device__ __forceinline__ unsigned short f2bf(float f) {
  unsigned int u = __float_as_uint(f);
  u += 0x7fff + ((u >> 16) & 1);
  return (unsigned short)(u >> 16);
}

__device__ __forceinline__ void async16(void* lds, const void* g) {
  __builtin_amdgcn_global_load_lds((const __attribute__((address_space(1))) void*)g,
                                   (__attribute__((address_space(3))) void*)lds,
                                   16, 0, 0);
}

// ---------------- convert fp32 -> bf16 (vectorized) ----------------
__global__ void cvt_bf16(const float* __restrict__ s, unsigned short* __restrict__ d, int n4) {
  int i = blockIdx.x * blockDim.x + threadIdx.x;
  if (i < n4) {
    float4 v = ((const float4*)s)[i];
    ushort4 o;
    o.x = f2bf(v.x); o.y = f2bf(v.y); o.z = f2bf(v.z); o.w = f2bf(v.w);
    ((ushort4*)d)[i] = o;
  }
}

// ---------------- gate: logits, softmax, top-2, counts ----------------
__global__ __launch_bounds__(64) void gate_kernel(
    const float* __restrict__ x, const float* __restrict__ gw,
    float* __restrict__ tw, int* __restrict__ ti, int* __restrict__ cnt) {
  int t = blockIdx.x;
  int l = threadIdx.x;
  const float* xr = x + (size_t)t * DIMSZ + l * 8;
  float xv[8];
#pragma unroll
  for (int j = 0; j < 8; ++j) xv[j] = xr[j];
  float p[NE];
#pragma unroll
  for (int e = 0; e < NE; ++e) {
    const float* gr = gw + e * DIMSZ + l * 8;
    float s = 0.f;
#pragma unroll
    for (int j = 0; j < 8; ++j) s += xv[j] * gr[j];
    p[e] = s;
  }
#pragma unroll
  for (int e = 0; e < NE; ++e) {
    float v = p[e];
#pragma unroll
    for (int off = 32; off > 0; off >>= 1) v += __shfl_xor(v, off);
    p[e] = v;
  }
  // softmax (fp32) — selection on logits == selection on probs (monotone)
  float m = p[0];
#pragma unroll
  for (int e = 1; e < NE; ++e) m = fmaxf(m, p[e]);
  float ex[NE], s = 0.f;
#pragma unroll
  for (int e = 0; e < NE; ++e) { ex[e] = __expf(p[e] - m); s += ex[e]; }
  float inv = 1.f / s;
  int e0 = 0; float v0 = p[0];
#pragma unroll
  for (int e = 1; e < NE; ++e) if (p[e] > v0) { v0 = p[e]; e0 = e; }
  int e1 = -1; float v1 = -3.4e38f;
#pragma unroll
  for (int e = 0; e < NE; ++e) if (e != e0 && p[e] > v1) { v1 = p[e]; e1 = e; }
  if (l == 0) {
    ti[2 * t] = e0;     tw[2 * t] = ex[e0] * inv;
    ti[2 * t + 1] = e1; tw[2 * t + 1] = ex[e1] * inv;
    atomicAdd(&cnt[e0], 1);
    atomicAdd(&cnt[e1], 1);
  }
}

// ---------------- exclusive scan over 8 expert counts ----------------
__global__ void scan_kernel(const int* __restrict__ cnt, int* __restrict__ base,
                            int* __restrict__ cursor) {
  if (threadIdx.x == 0 && blockIdx.x == 0) {
    int r = 0;
    for (int e = 0; e < NE; ++e) { base[e] = r; cursor[e] = r; r += cnt[e]; }
  }
}

// ---------------- scatter token ids into expert buckets ----------------
__global__ void scatter_kernel(const int* __restrict__ ti, int* __restrict__ cursor,
                               int* __restrict__ tok, int* __restrict__ dst) {
  int t = blockIdx.x * blockDim.x + threadIdx.x;
  if (t < T_TOK) {
#pragma unroll
    for (int k = 0; k < 2; ++k) {
      int e = ti[2 * t + k];
      int idx = atomicAdd(&cursor[e], 1);
      tok[idx] = t;
      dst[idx] = 2 * t + k;
    }
  }
}

// ---------------- gather bf16 x rows into bucket order ----------------
__global__ void gather_kernel(const unsigned short* __restrict__ xb,
                              const int* __restrict__ tok,
                              unsigned short* __restrict__ xg) {
  int i = blockIdx.x * blockDim.x + threadIdx.x;
  int entry = i >> 6, l = i & 63;
  int t = tok[entry];
  ((uint4*)xg)[entry * 64 + l] = ((const uint4*)xb)[t * 64 + l];
}

// ---------------- GEMM1: g = silu(A@W1^T) * (A@W3^T), bf16 out ----------------
// A: [rows, K] bf16 row-major (bucketed when ROUTED). W1/W3: [E][N][K]. G: [rows, N].
template <bool ROUTED>
__global__ __launch_bounds__(256, 2) void gemm1_kernel(
    const unsigned short* __restrict__ A0, const unsigned short* __restrict__ W1,
    const unsigned short* __restrict__ W3, unsigned short* __restrict__ G,
    const int* __restrict__ cnt, const int* __restrict__ base,
    int K, int N, int mtPerE) {
  int e, mt, cntE, rowbase;
  if constexpr (ROUTED) {
    e = blockIdx.x / mtPerE; mt = blockIdx.x % mtPerE;
    cntE = cnt[e];
    if (mt * 128 >= cntE) return;
    rowbase = base[e];
  } else {
    e = 0; mt = blockIdx.x; cntE = T_TOK; rowbase = 0;
  }
  const int m0 = mt * 128;
  const int n0 = blockIdx.y * 128;
  const unsigned short* A = A0 + (size_t)rowbase * K;
  const unsigned short* B1 = W1 + (size_t)e * N * K + (size_t)n0 * K;
  const unsigned short* B3 = W3 + (size_t)e * N * K + (size_t)n0 * K;

  __shared__ __align__(16) unsigned short As[128 * 32];
  __shared__ __align__(16) unsigned short B1s[128 * 32];
  __shared__ __align__(16) unsigned short B3s[128 * 32];

  const int tid = threadIdx.x;
  const int w = tid >> 6, lane = tid & 63;
  const int wr = w >> 1, wc = w & 1;
  const int lhi = lane >> 4, llo = lane & 15;

  const int idx0 = w * 128 + lane;
  const int idx1 = idx0 + 64;
  const int ra0 = idx0 >> 2, ca0 = (idx0 & 3) * 8;
  const int ra1 = idx1 >> 2, ca1 = (idx1 & 3) * 8;
  const int ar0 = ROUTED ? min(m0 + ra0, cntE - 1) : (m0 + ra0);
  const int ar1 = ROUTED ? min(m0 + ra1, cntE - 1) : (m0 + ra1);

  const unsigned short* gA0 = A + (size_t)ar0 * K + ca0;
  const unsigned short* gA1 = A + (size_t)ar1 * K + ca1;
  const unsigned short* gB1a = B1 + (size_t)ra0 * K + ca0;
  const unsigned short* gB1b = B1 + (size_t)ra1 * K + ca1;
  const unsigned short* gB3a = B3 + (size_t)ra0 * K + ca0;
  const unsigned short* gB3b = B3 + (size_t)ra1 * K + ca1;
  unsigned short* lA0 = &As[(w * 128) * 8];
  unsigned short* lA1 = &As[(w * 128 + 64) * 8];
  unsigned short* lB1a = &B1s[(w * 128) * 8];
  unsigned short* lB1b = &B1s[(w * 128 + 64) * 8];
  unsigned short* lB3a = &B3s[(w * 128) * 8];
  unsigned short* lB3b = &B3s[(w * 128 + 64) * 8];

  f32x4 acc1[4][4], acc3[4][4];
#pragma unroll
  for (int i = 0; i < 4; ++i)
#pragma unroll
    for (int j = 0; j < 4; ++j) {
      acc1[i][j] = f32x4{0.f, 0.f, 0.f, 0.f};
      acc3[i][j] = f32x4{0.f, 0.f, 0.f, 0.f};
    }

  for (int k0 = 0; k0 < K; k0 += 32) {
    async16(lA0, gA0 + k0);
    async16(lA1, gA1 + k0);
    async16(lB1a, gB1a + k0);
    async16(lB1b, gB1b + k0);
    async16(lB3a, gB3a + k0);
    async16(lB3b, gB3b + k0);
    __syncthreads();
    s16x8 a[4], b1[4], b3[4];
#pragma unroll
    for (int i = 0; i < 4; ++i)
      a[i] = *(const s16x8*)&As[(wr * 64 + i * 16 + llo) * 32 + lhi * 8];
#pragma unroll
    for (int j = 0; j < 4; ++j) {
      b1[j] = *(const s16x8*)&B1s[(wc * 64 + j * 16 + llo) * 32 + lhi * 8];
      b3[j] = *(const s16x8*)&B3s[(wc * 64 + j * 16 + llo) * 32 + lhi * 8];
    }
#pragma unroll
    for (int i = 0; i < 4; ++i)
#pragma unroll
      for (int j = 0; j < 4; ++j) {
        acc1[i][j] = __builtin_amdgcn_mfma_f32_16x16x32_bf16(a[i], b1[j], acc1[i][j], 0, 0, 0);
        acc3[i][j] = __builtin_amdgcn_mfma_f32_16x16x32_bf16(a[i], b3[j], acc3[i][j], 0, 0, 0);
      }
    __syncthreads();
  }

  unsigned short* Grow = G + (size_t)rowbase * N;
#pragma unroll
  for (int i = 0; i < 4; ++i)
#pragma unroll
    for (int j = 0; j < 4; ++j)
#pragma unroll
      for (int q = 0; q < 4; ++q) {
        int r = wr * 64 + i * 16 + lhi * 4 + q;
        if (!ROUTED || (m0 + r) < cntE) {
          float h1 = acc1[i][j][q], h3 = acc3[i][j][q];
          float val = (h1 / (1.f + __expf(-h1))) * h3;
          Grow[(size_t)(m0 + r) * N + n0 + wc * 64 + j * 16 + llo] = f2bf(val);
        }
      }
}

// ---------------- GEMM2: out = A@W2^T (fp32 out, scattered when ROUTED) --------
// A: [rows, K] bf16 (bucketed g when ROUTED). W2: [E][512][K]. Out fp32.
template <bool ROUTED>
__global__ __launch_bounds__(256, 2) void gemm2_kernel(
    const unsigned short* __restrict__ A0, const unsigned short* __restrict__ W2,
    float* __restrict__ Out, const int* __restrict__ cnt, const int* __restrict__ base,
    const int* __restrict__ dst, int K, int mtPerE) {
  int e, mt, cntE, rowbase;
  if constexpr (ROUTED) {
    e = blockIdx.x / mtPerE; mt = blockIdx.x % mtPerE;
    cntE = cnt[e];
    if (mt * 128 >= cntE) return;
    rowbase = base[e];
  } else {
    e = 0; mt = blockIdx.x; cntE = T_TOK; rowbase = 0;
  }
  const int m0 = mt * 128;
  const int n0 = blockIdx.y * 128;
  const unsigned short* A = A0 + (size_t)rowbase * K;
  const unsigned short* B = W2 + (size_t)e * DIMSZ * K + (size_t)n0 * K;

  __shared__ __align__(16) unsigned short As[128 * 32];
  __shared__ __align__(16) unsigned short Bs[128 * 32];

  const int tid = threadIdx.x;
  const int w = tid >> 6, lane = tid & 63;
  const int wr = w >> 1, wc = w & 1;
  const int lhi = lane >> 4, llo = lane & 15;

  const int idx0 = w * 128 + lane;
  const int idx1 = idx0 + 64;
  const int ra0 = idx0 >> 2, ca0 = (idx0 & 3) * 8;
  const int ra1 = idx1 >> 2, ca1 = (idx1 & 3) * 8;
  const int ar0 = ROUTED ? min(m0 + ra0, cntE - 1) : (m0 + ra0);
  const int ar1 = ROUTED ? min(m0 + ra1, cntE - 1) : (m0 + ra1);

  const unsigned short* gA0 = A + (size_t)ar0 * K + ca0;
  const unsigned short* gA1 = A + (size_t)ar1 * K + ca1;
  const unsigned short* gBa = B + (size_t)ra0 * K + ca0;
  const unsigned short* gBb = B + (size_t)ra1 * K + ca1;
  unsigned short* lA0 = &As[(w * 128) * 8];
  unsigned short* lA1 = &As[(w * 128 + 64) * 8];
  unsigned short* lBa = &Bs[(w * 128) * 8];
  unsigned short* lBb = &Bs[(w * 128 + 64) * 8];

  f32x4 acc[4][4];
#pragma unroll
  for (int i = 0; i < 4; ++i)
#pragma unroll
    for (int j = 0; j < 4; ++j) acc[i][j] = f32x4{0.f, 0.f, 0.f, 0.f};

  for (int k0 = 0; k0 < K; k0 += 32) {
    async16(lA0, gA0 + k0);
    async16(lA1, gA1 + k0);
    async16(lBa, gBa + k0);
    async16(lBb, gBb + k0);
    __syncthreads();
    s16x8 a[4], b[4];
#pragma unroll
    for (int i = 0; i < 4; ++i)
      a[i] = *(const s16x8*)&As[(wr * 64 + i * 16 + llo) * 32 + lhi * 8];
#pragma unroll
    for (int j = 0; j < 4; ++j)
      b[j] = *(const s16x8*)&Bs[(wc * 64 + j * 16 + llo) * 32 + lhi * 8];
#pragma unroll
    for (int i = 0; i < 4; ++i)
#pragma unroll
      for (int j = 0; j < 4; ++j)
        acc[i][j] = __builtin_amdgcn_mfma_f32_16x16x32_bf16(a[i], b[j], acc[i][j], 0, 0, 0);
    __syncthreads();
  }

#pragma unroll
  for (int i = 0; i < 4; ++i)
#pragma unroll
    for (int j = 0; j < 4; ++j)
#pragma unroll
      for (int q = 0; q < 4; ++q) {
        int r = wr * 64 + i * 16 + lhi * 4 + q;
        if (!ROUTED || (m0 + r) < cntE) {
          int orow;
          if constexpr (ROUTED) orow = dst[rowbase + m0 + r];
          else                  orow = m0 + r;
          Out[(size_t)orow * DIMSZ + n0 + wc * 64 + j * 16 + llo] = acc[i][j][q];
        }
      }
}

// ---------------- final combine: out = shared + w0*p0 + w1*p1 ----------------
__global__ void combine_kernel(const float* __restrict__ shbuf, const float* __restrict__ pair,
                               const float* __restrict__ tw, float* __restrict__ out) {
  int i = blockIdx.x * blockDim.x + threadIdx.x;  // float4 index over T*128
  int t = i >> 7, c = i & 127;
  float w0 = tw[2 * t], w1 = tw[2 * t + 1];
  float4 a = ((const float4*)shbuf)[i];
  float4 p0 = ((const float4*)pair)[(size_t)(2 * t) * 128 + c];
  float4 p1 = ((const float4*)pair)[(size_t)(2 * t + 1) * 128 + c];
  float4 o;
  o.x = a.x + w0 * p0.x + w1 * p1.x;
  o.y = a.y + w0 * p0.y + w1 * p1.y;
  o.z = a.z + w0 * p0.z + w1 * p1.z;
  o.w = a.w + w0 * p0.w + w1 * p1.w;
  ((float4*)out)[i] = o;
}

extern "C" void kernel_launch(void* const* d_in, const int* in_sizes, int n_in,
                              void* d_out, int out_size, void* d_ws, size_t ws_size,
                              hipStream_t stream) {
  const float* x   = (const float*)d_in[0];
  const float* gw  = (const float*)d_in[1];
  const float* w1  = (const float*)d_in[2];
  const float* w3  = (const float*)d_in[3];
  const float* w2  = (const float*)d_in[4];
  const float* sw1 = (const float*)d_in[5];
  const float* sw3 = (const float*)d_in[6];
  const float* sw2 = (const float*)d_in[7];
  float* out = (float*)d_out;

  char* p = (char*)d_ws;
  auto alloc = [&](size_t bytes) {
    char* r = p;
    p += (bytes + 255) & ~(size_t)255;
    return r;
  };
  unsigned short* xb   = (unsigned short*)alloc((size_t)T_TOK * DIMSZ * 2);
  unsigned short* xg   = (unsigned short*)alloc((size_t)2 * T_TOK * DIMSZ * 2);
  unsigned short* w1b  = (unsigned short*)alloc((size_t)NE * HIDSZ * DIMSZ * 2);
  unsigned short* w3b  = (unsigned short*)alloc((size_t)NE * HIDSZ * DIMSZ * 2);
  unsigned short* w2b  = (unsigned short*)alloc((size_t)NE * DIMSZ * HIDSZ * 2);
  unsigned short* sw1b = (unsigned short*)alloc((size_t)SHIDSZ * DIMSZ * 2);
  unsigned short* sw3b = (unsigned short*)alloc((size_t)SHIDSZ * DIMSZ * 2);
  unsigned short* sw2b = (unsigned short*)alloc((size_t)DIMSZ * SHIDSZ * 2);
  // g doubles as g_sh ([8192,3072]) then as routed g ([16384,1536]) — same byte size
  unsigned short* g    = (unsigned short*)alloc((size_t)T_TOK * SHIDSZ * 2);
  float* pairout = (float*)alloc((size_t)2 * T_TOK * DIMSZ * 4);
  float* shbuf   = (float*)alloc((size_t)T_TOK * DIMSZ * 4);
  float* tw = (float*)alloc((size_t)2 * T_TOK * 4);
  int* ti   = (int*)alloc((size_t)2 * T_TOK * 4);
  int* tok  = (int*)alloc((size_t)2 * T_TOK * 4);
  int* dst  = (int*)alloc((size_t)2 * T_TOK * 4);
  int* meta = (int*)alloc(256);
  int* cnt = meta, *cursor = meta + 8, *base = meta + 16;

  auto cvt = [&](const float* s, unsigned short* d, size_t n) {
    int n4 = (int)(n / 4);
    cvt_bf16<<<(n4 + 255) / 256, 256, 0, stream>>>(s, d, n4);
  };
  cvt(x, xb, (size_t)T_TOK * DIMSZ);
  cvt(w1, w1b, (size_t)NE * HIDSZ * DIMSZ);
  cvt(w3, w3b, (size_t)NE * HIDSZ * DIMSZ);
  cvt(w2, w2b, (size_t)NE * DIMSZ * HIDSZ);
  cvt(sw1, sw1b, (size_t)SHIDSZ * DIMSZ);
  cvt(sw3, sw3b, (size_t)SHIDSZ * DIMSZ);
  cvt(sw2, sw2b, (size_t)DIMSZ * SHIDSZ);

  hipMemsetAsync(meta, 0, 64, stream);
  gate_kernel<<<T_TOK, 64, 0, stream>>>(x, gw, tw, ti, cnt);
  scan_kernel<<<1, 64, 0, stream>>>(cnt, base, cursor);
  scatter_kernel<<<T_TOK / 256, 256, 0, stream>>>(ti, cursor, tok, dst);
  gather_kernel<<<(2 * T_TOK * 64) / 256, 256, 0, stream>>>(xb, tok, xg);

  // shared expert (dense) — uses g buffer as [8192, 3072]
  gemm1_kernel<false><<<dim3(T_TOK / 128, SHIDSZ / 128), 256, 0, stream>>>(
      xb, sw1b, sw3b, g, nullptr, nullptr, DIMSZ, SHIDSZ, T_TOK / 128);
  gemm2_kernel<false><<<dim3(T_TOK / 128, DIMSZ / 128), 256, 0, stream>>>(
      g, sw2b, shbuf, nullptr, nullptr, nullptr, SHIDSZ, T_TOK / 128);

  // routed experts — g buffer reused as [16384, 1536]
  gemm1_kernel<true><<<dim3(NE * (T_TOK / 128), HIDSZ / 128), 256, 0, stream>>>(
      xg, w1b, w3b, g, cnt, base, DIMSZ, HIDSZ, T_TOK / 128);
  gemm2_kernel<true><<<dim3(NE * (T_TOK / 128), DIMSZ / 128), 256, 0, stream>>>(
      g, w2b, pairout, cnt, base, dst, HIDSZ, T_TOK / 128);

  combine_kernel<<<(T_TOK * 128) / 256, 256, 0, stream>>>(shbuf, pairout, tw, out);
}

// Round 3
// 526.207 us; speedup vs baseline: 1.4578x; 1.4578x over previous
//
#include <hip/hip_runtime.h>

#define T_TOK 8192
#define DIMSZ 512
#define HIDSZ 1536
#define SHIDSZ 3072
#define NE 8

typedef __attribute__((ext_vector_type(4))) float f32x4;
typedef __attribute__((ext_vector_type(8))) short s16x8;

__device__ __forceinline__ unsigned short f2bf(float f) {
  unsigned int u = __float_as_uint(f);
  u += 0x7fff + ((u >> 16) & 1);
  return (unsigned short)(u >> 16);
}

__device__ __forceinline__ void async16(void* lds, const void* g) {
  __builtin_amdgcn_global_load_lds((const __attribute__((address_space(1))) void*)g,
                                   (__attribute__((address_space(3))) void*)lds,
                                   16, 0, 0);
}

// ---------------- convert fp32 -> bf16 (vectorized) ----------------
__global__ void cvt_bf16(const float* __restrict__ s, unsigned short* __restrict__ d, int n4) {
  int i = blockIdx.x * blockDim.x + threadIdx.x;
  if (i < n4) {
    float4 v = ((const float4*)s)[i];
    ushort4 o;
    o.x = f2bf(v.x); o.y = f2bf(v.y); o.z = f2bf(v.z); o.w = f2bf(v.w);
    ((ushort4*)d)[i] = o;
  }
}

// ---------------- gate: logits, softmax, top-2, block-aggregated counts ------
// 256 blocks x 256 threads (4 waves). Each wave handles 8 tokens; gate weights
// hoisted into registers once per wave. LDS histogram -> 8 global atomics/block.
#define GATE_BLOCKS 256
#define GATE_TPB (T_TOK / GATE_BLOCKS)   // 32 tokens per block
#define GATE_TPW (GATE_TPB / 4)          // 8 tokens per wave

__global__ __launch_bounds__(256) void gate_kernel(
    const float* __restrict__ x, const float* __restrict__ gw,
    float* __restrict__ tw, int* __restrict__ ti, int* __restrict__ cnt) {
  __shared__ int lcnt[NE];
  const int tid = threadIdx.x;
  if (tid < NE) lcnt[tid] = 0;
  __syncthreads();
  const int w = tid >> 6, l = tid & 63;

  float gv[NE][8];
  const float* gbase = gw + l * 8;
#pragma unroll
  for (int e = 0; e < NE; ++e)
#pragma unroll
    for (int j = 0; j < 8; ++j) gv[e][j] = gbase[e * DIMSZ + j];

  const int tok0 = blockIdx.x * GATE_TPB + w * GATE_TPW;
  for (int it = 0; it < GATE_TPW; ++it) {
    const int t = tok0 + it;
    const float* xr = x + (size_t)t * DIMSZ + l * 8;
    float xv[8];
#pragma unroll
    for (int j = 0; j < 8; ++j) xv[j] = xr[j];
    float p[NE];
#pragma unroll
    for (int e = 0; e < NE; ++e) {
      float s = 0.f;
#pragma unroll
      for (int j = 0; j < 8; ++j) s = fmaf(xv[j], gv[e][j], s);
      p[e] = s;
    }
#pragma unroll
    for (int e = 0; e < NE; ++e) {
      float v = p[e];
#pragma unroll
      for (int off = 32; off > 0; off >>= 1) v += __shfl_xor(v, off);
      p[e] = v;
    }
    // softmax (fp32); selection on logits == selection on probs (monotone).
    float m = p[0];
#pragma unroll
    for (int e = 1; e < NE; ++e) m = fmaxf(m, p[e]);
    float ex[NE], s = 0.f;
#pragma unroll
    for (int e = 0; e < NE; ++e) { ex[e] = __expf(p[e] - m); s += ex[e]; }
    float inv = 1.f / s;
    int e0 = 0; float v0 = p[0];
#pragma unroll
    for (int e = 1; e < NE; ++e) if (p[e] > v0) { v0 = p[e]; e0 = e; }
    int e1 = -1; float v1 = -3.4e38f;
#pragma unroll
    for (int e = 0; e < NE; ++e) if (e != e0 && p[e] > v1) { v1 = p[e]; e1 = e; }
    if (l == 0) {
      ti[2 * t] = e0;     tw[2 * t] = ex[e0] * inv;
      ti[2 * t + 1] = e1; tw[2 * t + 1] = ex[e1] * inv;
      atomicAdd(&lcnt[e0], 1);
      atomicAdd(&lcnt[e1], 1);
    }
  }
  __syncthreads();
  if (tid < NE) atomicAdd(&cnt[tid], lcnt[tid]);
}

// ---------------- exclusive scan over 8 expert counts ----------------
__global__ void scan_kernel(const int* __restrict__ cnt, int* __restrict__ base,
                            int* __restrict__ cursor) {
  if (threadIdx.x == 0 && blockIdx.x == 0) {
    int r = 0;
    for (int e = 0; e < NE; ++e) { base[e] = r; cursor[e] = r; r += cnt[e]; }
  }
}

// ---------------- scatter token ids into expert buckets (block-aggregated) ----
// 32 blocks x 256 threads; thread owns one token (2 entries). Local position via
// LDS atomics, one global atomicAdd per expert per block reserves the range.
__global__ __launch_bounds__(256) void scatter_kernel(
    const int* __restrict__ ti, int* __restrict__ cursor,
    int* __restrict__ tok, int* __restrict__ dst) {
  __shared__ int lcnt[NE], gbase[NE];
  const int tid = threadIdx.x;
  if (tid < NE) lcnt[tid] = 0;
  __syncthreads();
  const int t = blockIdx.x * 256 + tid;
  const int e0 = ti[2 * t], e1 = ti[2 * t + 1];
  const int p0 = atomicAdd(&lcnt[e0], 1);
  const int p1 = atomicAdd(&lcnt[e1], 1);
  __syncthreads();
  if (tid < NE) gbase[tid] = atomicAdd(&cursor[tid], lcnt[tid]);
  __syncthreads();
  const int i0 = gbase[e0] + p0, i1 = gbase[e1] + p1;
  tok[i0] = t; dst[i0] = 2 * t;
  tok[i1] = t; dst[i1] = 2 * t + 1;
}

// ---------------- gather bf16 x rows into bucket order ----------------
__global__ void gather_kernel(const unsigned short* __restrict__ xb,
                              const int* __restrict__ tok,
                              unsigned short* __restrict__ xg) {
  int i = blockIdx.x * blockDim.x + threadIdx.x;
  int entry = i >> 6, l = i & 63;
  int t = tok[entry];
  ((uint4*)xg)[entry * 64 + l] = ((const uint4*)xb)[t * 64 + l];
}

// ---------------- GEMM1: g = silu(A@W1^T) * (A@W3^T), bf16 out ----------------
// A: [rows, K] bf16 row-major (bucketed when ROUTED). W1/W3: [E][N][K]. G: [rows, N].
template <bool ROUTED>
__global__ __launch_bounds__(256, 2) void gemm1_kernel(
    const unsigned short* __restrict__ A0, const unsigned short* __restrict__ W1,
    const unsigned short* __restrict__ W3, unsigned short* __restrict__ G,
    const int* __restrict__ cnt, const int* __restrict__ base,
    int K, int N, int mtPerE) {
  int e, mt, cntE, rowbase;
  if constexpr (ROUTED) {
    e = blockIdx.x / mtPerE; mt = blockIdx.x % mtPerE;
    cntE = cnt[e];
    if (mt * 128 >= cntE) return;
    rowbase = base[e];
  } else {
    e = 0; mt = blockIdx.x; cntE = T_TOK; rowbase = 0;
  }
  const int m0 = mt * 128;
  const int n0 = blockIdx.y * 128;
  const unsigned short* A = A0 + (size_t)rowbase * K;
  const unsigned short* B1 = W1 + (size_t)e * N * K + (size_t)n0 * K;
  const unsigned short* B3 = W3 + (size_t)e * N * K + (size_t)n0 * K;

  __shared__ __align__(16) unsigned short As[128 * 32];
  __shared__ __align__(16) unsigned short B1s[128 * 32];
  __shared__ __align__(16) unsigned short B3s[128 * 32];

  const int tid = threadIdx.x;
  const int w = tid >> 6, lane = tid & 63;
  const int wr = w >> 1, wc = w & 1;
  const int lhi = lane >> 4, llo = lane & 15;

  const int idx0 = w * 128 + lane;
  const int idx1 = idx0 + 64;
  const int ra0 = idx0 >> 2, ca0 = (idx0 & 3) * 8;
  const int ra1 = idx1 >> 2, ca1 = (idx1 & 3) * 8;
  const int ar0 = ROUTED ? min(m0 + ra0, cntE - 1) : (m0 + ra0);
  const int ar1 = ROUTED ? min(m0 + ra1, cntE - 1) : (m0 + ra1);

  const unsigned short* gA0 = A + (size_t)ar0 * K + ca0;
  const unsigned short* gA1 = A + (size_t)ar1 * K + ca1;
  const unsigned short* gB1a = B1 + (size_t)ra0 * K + ca0;
  const unsigned short* gB1b = B1 + (size_t)ra1 * K + ca1;
  const unsigned short* gB3a = B3 + (size_t)ra0 * K + ca0;
  const unsigned short* gB3b = B3 + (size_t)ra1 * K + ca1;
  unsigned short* lA0 = &As[(w * 128) * 8];
  unsigned short* lA1 = &As[(w * 128 + 64) * 8];
  unsigned short* lB1a = &B1s[(w * 128) * 8];
  unsigned short* lB1b = &B1s[(w * 128 + 64) * 8];
  unsigned short* lB3a = &B3s[(w * 128) * 8];
  unsigned short* lB3b = &B3s[(w * 128 + 64) * 8];

  f32x4 acc1[4][4], acc3[4][4];
#pragma unroll
  for (int i = 0; i < 4; ++i)
#pragma unroll
    for (int j = 0; j < 4; ++j) {
      acc1[i][j] = f32x4{0.f, 0.f, 0.f, 0.f};
      acc3[i][j] = f32x4{0.f, 0.f, 0.f, 0.f};
    }

  for (int k0 = 0; k0 < K; k0 += 32) {
    async16(lA0, gA0 + k0);
    async16(lA1, gA1 + k0);
    async16(lB1a, gB1a + k0);
    async16(lB1b, gB1b + k0);
    async16(lB3a, gB3a + k0);
    async16(lB3b, gB3b + k0);
    __syncthreads();
    s16x8 a[4], b1[4], b3[4];
#pragma unroll
    for (int i = 0; i < 4; ++i)
      a[i] = *(const s16x8*)&As[(wr * 64 + i * 16 + llo) * 32 + lhi * 8];
#pragma unroll
    for (int j = 0; j < 4; ++j) {
      b1[j] = *(const s16x8*)&B1s[(wc * 64 + j * 16 + llo) * 32 + lhi * 8];
      b3[j] = *(const s16x8*)&B3s[(wc * 64 + j * 16 + llo) * 32 + lhi * 8];
    }
#pragma unroll
    for (int i = 0; i < 4; ++i)
#pragma unroll
      for (int j = 0; j < 4; ++j) {
        acc1[i][j] = __builtin_amdgcn_mfma_f32_16x16x32_bf16(a[i], b1[j], acc1[i][j], 0, 0, 0);
        acc3[i][j] = __builtin_amdgcn_mfma_f32_16x16x32_bf16(a[i], b3[j], acc3[i][j], 0, 0, 0);
      }
    __syncthreads();
  }

  unsigned short* Grow = G + (size_t)rowbase * N;
#pragma unroll
  for (int i = 0; i < 4; ++i)
#pragma unroll
    for (int j = 0; j < 4; ++j)
#pragma unroll
      for (int q = 0; q < 4; ++q) {
        int r = wr * 64 + i * 16 + lhi * 4 + q;
        if (!ROUTED || (m0 + r) < cntE) {
          float h1 = acc1[i][j][q], h3 = acc3[i][j][q];
          float val = (h1 / (1.f + __expf(-h1))) * h3;
          Grow[(size_t)(m0 + r) * N + n0 + wc * 64 + j * 16 + llo] = f2bf(val);
        }
      }
}

// ---------------- GEMM2: out = A@W2^T (fp32 out, scattered when ROUTED) --------
// A: [rows, K] bf16 (bucketed g when ROUTED). W2: [E][512][K]. Out fp32.
template <bool ROUTED>
__global__ __launch_bounds__(256, 2) void gemm2_kernel(
    const unsigned short* __restrict__ A0, const unsigned short* __restrict__ W2,
    float* __restrict__ Out, const int* __restrict__ cnt, const int* __restrict__ base,
    const int* __restrict__ dst, int K, int mtPerE) {
  int e, mt, cntE, rowbase;
  if constexpr (ROUTED) {
    e = blockIdx.x / mtPerE; mt = blockIdx.x % mtPerE;
    cntE = cnt[e];
    if (mt * 128 >= cntE) return;
    rowbase = base[e];
  } else {
    e = 0; mt = blockIdx.x; cntE = T_TOK; rowbase = 0;
  }
  const int m0 = mt * 128;
  const int n0 = blockIdx.y * 128;
  const unsigned short* A = A0 + (size_t)rowbase * K;
  const unsigned short* B = W2 + (size_t)e * DIMSZ * K + (size_t)n0 * K;

  __shared__ __align__(16) unsigned short As[128 * 32];
  __shared__ __align__(16) unsigned short Bs[128 * 32];

  const int tid = threadIdx.x;
  const int w = tid >> 6, lane = tid & 63;
  const int wr = w >> 1, wc = w & 1;
  const int lhi = lane >> 4, llo = lane & 15;

  const int idx0 = w * 128 + lane;
  const int idx1 = idx0 + 64;
  const int ra0 = idx0 >> 2, ca0 = (idx0 & 3) * 8;
  const int ra1 = idx1 >> 2, ca1 = (idx1 & 3) * 8;
  const int ar0 = ROUTED ? min(m0 + ra0, cntE - 1) : (m0 + ra0);
  const int ar1 = ROUTED ? min(m0 + ra1, cntE - 1) : (m0 + ra1);

  const unsigned short* gA0 = A + (size_t)ar0 * K + ca0;
  const unsigned short* gA1 = A + (size_t)ar1 * K + ca1;
  const unsigned short* gBa = B + (size_t)ra0 * K + ca0;
  const unsigned short* gBb = B + (size_t)ra1 * K + ca1;
  unsigned short* lA0 = &As[(w * 128) * 8];
  unsigned short* lA1 = &As[(w * 128 + 64) * 8];
  unsigned short* lBa = &Bs[(w * 128) * 8];
  unsigned short* lBb = &Bs[(w * 128 + 64) * 8];

  f32x4 acc[4][4];
#pragma unroll
  for (int i = 0; i < 4; ++i)
#pragma unroll
    for (int j = 0; j < 4; ++j) acc[i][j] = f32x4{0.f, 0.f, 0.f, 0.f};

  for (int k0 = 0; k0 < K; k0 += 32) {
    async16(lA0, gA0 + k0);
    async16(lA1, gA1 + k0);
    async16(lBa, gBa + k0);
    async16(lBb, gBb + k0);
    __syncthreads();
    s16x8 a[4], b[4];
#pragma unroll
    for (int i = 0; i < 4; ++i)
      a[i] = *(const s16x8*)&As[(wr * 64 + i * 16 + llo) * 32 + lhi * 8];
#pragma unroll
    for (int j = 0; j < 4; ++j)
      b[j] = *(const s16x8*)&Bs[(wc * 64 + j * 16 + llo) * 32 + lhi * 8];
#pragma unroll
    for (int i = 0; i < 4; ++i)
#pragma unroll
      for (int j = 0; j < 4; ++j)
        acc[i][j] = __builtin_amdgcn_mfma_f32_16x16x32_bf16(a[i], b[j], acc[i][j], 0, 0, 0);
    __syncthreads();
  }

#pragma unroll
  for (int i = 0; i < 4; ++i)
#pragma unroll
    for (int j = 0; j < 4; ++j)
#pragma unroll
      for (int q = 0; q < 4; ++q) {
        int r = wr * 64 + i * 16 + lhi * 4 + q;
        if (!ROUTED || (m0 + r) < cntE) {
          int orow;
          if constexpr (ROUTED) orow = dst[rowbase + m0 + r];
          else                  orow = m0 + r;
          Out[(size_t)orow * DIMSZ + n0 + wc * 64 + j * 16 + llo] = acc[i][j][q];
        }
      }
}

// ---------------- final combine: out = shared + w0*p0 + w1*p1 ----------------
__global__ void combine_kernel(const float* __restrict__ shbuf, const float* __restrict__ pair,
                               const float* __restrict__ tw, float* __restrict__ out) {
  int i = blockIdx.x * blockDim.x + threadIdx.x;  // float4 index over T*128
  int t = i >> 7, c = i & 127;
  float w0 = tw[2 * t], w1 = tw[2 * t + 1];
  float4 a = ((const float4*)shbuf)[i];
  float4 p0 = ((const float4*)pair)[(size_t)(2 * t) * 128 + c];
  float4 p1 = ((const float4*)pair)[(size_t)(2 * t + 1) * 128 + c];
  float4 o;
  o.x = a.x + w0 * p0.x + w1 * p1.x;
  o.y = a.y + w0 * p0.y + w1 * p1.y;
  o.z = a.z + w0 * p0.z + w1 * p1.z;
  o.w = a.w + w0 * p0.w + w1 * p1.w;
  ((float4*)out)[i] = o;
}

extern "C" void kernel_launch(void* const* d_in, const int* in_sizes, int n_in,
                              void* d_out, int out_size, void* d_ws, size_t ws_size,
                              hipStream_t stream) {
  const float* x   = (const float*)d_in[0];
  const float* gw  = (const float*)d_in[1];
  const float* w1  = (const float*)d_in[2];
  const float* w3  = (const float*)d_in[3];
  const float* w2  = (const float*)d_in[4];
  const float* sw1 = (const float*)d_in[5];
  const float* sw3 = (const float*)d_in[6];
  const float* sw2 = (const float*)d_in[7];
  float* out = (float*)d_out;

  char* p = (char*)d_ws;
  auto alloc = [&](size_t bytes) {
    char* r = p;
    p += (bytes + 255) & ~(size_t)255;
    return r;
  };
  unsigned short* xb   = (unsigned short*)alloc((size_t)T_TOK * DIMSZ * 2);
  unsigned short* xg   = (unsigned short*)alloc((size_t)2 * T_TOK * DIMSZ * 2);
  unsigned short* w1b  = (unsigned short*)alloc((size_t)NE * HIDSZ * DIMSZ * 2);
  unsigned short* w3b  = (unsigned short*)alloc((size_t)NE * HIDSZ * DIMSZ * 2);
  unsigned short* w2b  = (unsigned short*)alloc((size_t)NE * DIMSZ * HIDSZ * 2);
  unsigned short* sw1b = (unsigned short*)alloc((size_t)SHIDSZ * DIMSZ * 2);
  unsigned short* sw3b = (unsigned short*)alloc((size_t)SHIDSZ * DIMSZ * 2);
  unsigned short* sw2b = (unsigned short*)alloc((size_t)DIMSZ * SHIDSZ * 2);
  // g doubles as g_sh ([8192,3072]) then as routed g ([16384,1536]) — same byte size
  unsigned short* g    = (unsigned short*)alloc((size_t)T_TOK * SHIDSZ * 2);
  float* pairout = (float*)alloc((size_t)2 * T_TOK * DIMSZ * 4);
  float* shbuf   = (float*)alloc((size_t)T_TOK * DIMSZ * 4);
  float* tw = (float*)alloc((size_t)2 * T_TOK * 4);
  int* ti   = (int*)alloc((size_t)2 * T_TOK * 4);
  int* tok  = (int*)alloc((size_t)2 * T_TOK * 4);
  int* dst  = (int*)alloc((size_t)2 * T_TOK * 4);
  int* meta = (int*)alloc(256);
  int* cnt = meta, *cursor = meta + 8, *base = meta + 16;

  auto cvt = [&](const float* s, unsigned short* d, size_t n) {
    int n4 = (int)(n / 4);
    cvt_bf16<<<(n4 + 255) / 256, 256, 0, stream>>>(s, d, n4);
  };
  cvt(x, xb, (size_t)T_TOK * DIMSZ);
  cvt(w1, w1b, (size_t)NE * HIDSZ * DIMSZ);
  cvt(w3, w3b, (size_t)NE * HIDSZ * DIMSZ);
  cvt(w2, w2b, (size_t)NE * DIMSZ * HIDSZ);
  cvt(sw1, sw1b, (size_t)SHIDSZ * DIMSZ);
  cvt(sw3, sw3b, (size_t)SHIDSZ * DIMSZ);
  cvt(sw2, sw2b, (size_t)DIMSZ * SHIDSZ);

  hipMemsetAsync(meta, 0, 64, stream);
  gate_kernel<<<GATE_BLOCKS, 256, 0, stream>>>(x, gw, tw, ti, cnt);
  scan_kernel<<<1, 64, 0, stream>>>(cnt, base, cursor);
  scatter_kernel<<<T_TOK / 256, 256, 0, stream>>>(ti, cursor, tok, dst);
  gather_kernel<<<(2 * T_TOK * 64) / 256, 256, 0, stream>>>(xb, tok, xg);

  // shared expert (dense) — uses g buffer as [8192, 3072]
  gemm1_kernel<false><<<dim3(T_TOK / 128, SHIDSZ / 128), 256, 0, stream>>>(
      xb, sw1b, sw3b, g, nullptr, nullptr, DIMSZ, SHIDSZ, T_TOK / 128);
  gemm2_kernel<false><<<dim3(T_TOK / 128, DIMSZ / 128), 256, 0, stream>>>(
      g, sw2b, shbuf, nullptr, nullptr, nullptr, SHIDSZ, T_TOK / 128);

  // routed experts — g buffer reused as [16384, 1536]
  gemm1_kernel<true><<<dim3(NE * (T_TOK / 128), HIDSZ / 128), 256, 0, stream>>>(
      xg, w1b, w3b, g, cnt, base, DIMSZ, HIDSZ, T_TOK / 128);
  gemm2_kernel<true><<<dim3(NE * (T_TOK / 128), DIMSZ / 128), 256, 0, stream>>>(
      g, w2b, pairout, cnt, base, dst, HIDSZ, T_TOK / 128);

  combine_kernel<<<(T_TOK * 128) / 256, 256, 0, stream>>>(shbuf, pairout, tw, out);
}

// Round 4
// 448.735 us; speedup vs baseline: 1.7095x; 1.1726x over previous
//
#include <hip/hip_runtime.h>

#define T_TOK 8192
#define DIMSZ 512
#define HIDSZ 1536
#define SHIDSZ 3072
#define NE 8

typedef __attribute__((ext_vector_type(4))) float f32x4;
typedef __attribute__((ext_vector_type(8))) short s16x8;

__device__ __forceinline__ unsigned short f2bf(float f) {
  unsigned int u = __float_as_uint(f);
  u += 0x7fff + ((u >> 16) & 1);
  return (unsigned short)(u >> 16);
}

__device__ __forceinline__ void async16(void* lds, const void* g) {
  __builtin_amdgcn_global_load_lds((const __attribute__((address_space(1))) void*)g,
                                   (__attribute__((address_space(3))) void*)lds,
                                   16, 0, 0);
}

// ---------------- convert fp32 -> bf16 (vectorized) ----------------
__global__ void cvt_bf16(const float* __restrict__ s, unsigned short* __restrict__ d, int n4) {
  int i = blockIdx.x * blockDim.x + threadIdx.x;
  if (i < n4) {
    float4 v = ((const float4*)s)[i];
    ushort4 o;
    o.x = f2bf(v.x); o.y = f2bf(v.y); o.z = f2bf(v.z); o.w = f2bf(v.w);
    ((ushort4*)d)[i] = o;
  }
}

// ---------------- gate: logits, softmax, top-2, block-aggregated counts ------
#define GATE_BLOCKS 256
#define GATE_TPB (T_TOK / GATE_BLOCKS)
#define GATE_TPW (GATE_TPB / 4)

__global__ __launch_bounds__(256) void gate_kernel(
    const float* __restrict__ x, const float* __restrict__ gw,
    float* __restrict__ tw, int* __restrict__ ti, int* __restrict__ cnt) {
  __shared__ int lcnt[NE];
  const int tid = threadIdx.x;
  if (tid < NE) lcnt[tid] = 0;
  __syncthreads();
  const int w = tid >> 6, l = tid & 63;

  float gv[NE][8];
  const float* gbase = gw + l * 8;
#pragma unroll
  for (int e = 0; e < NE; ++e)
#pragma unroll
    for (int j = 0; j < 8; ++j) gv[e][j] = gbase[e * DIMSZ + j];

  const int tok0 = blockIdx.x * GATE_TPB + w * GATE_TPW;
  for (int it = 0; it < GATE_TPW; ++it) {
    const int t = tok0 + it;
    const float* xr = x + (size_t)t * DIMSZ + l * 8;
    float xv[8];
#pragma unroll
    for (int j = 0; j < 8; ++j) xv[j] = xr[j];
    float p[NE];
#pragma unroll
    for (int e = 0; e < NE; ++e) {
      float s = 0.f;
#pragma unroll
      for (int j = 0; j < 8; ++j) s = fmaf(xv[j], gv[e][j], s);
      p[e] = s;
    }
#pragma unroll
    for (int e = 0; e < NE; ++e) {
      float v = p[e];
#pragma unroll
      for (int off = 32; off > 0; off >>= 1) v += __shfl_xor(v, off);
      p[e] = v;
    }
    float m = p[0];
#pragma unroll
    for (int e = 1; e < NE; ++e) m = fmaxf(m, p[e]);
    float ex[NE], s = 0.f;
#pragma unroll
    for (int e = 0; e < NE; ++e) { ex[e] = __expf(p[e] - m); s += ex[e]; }
    float inv = 1.f / s;
    int e0 = 0; float v0 = p[0];
#pragma unroll
    for (int e = 1; e < NE; ++e) if (p[e] > v0) { v0 = p[e]; e0 = e; }
    int e1 = -1; float v1 = -3.4e38f;
#pragma unroll
    for (int e = 0; e < NE; ++e) if (e != e0 && p[e] > v1) { v1 = p[e]; e1 = e; }
    if (l == 0) {
      ti[2 * t] = e0;     tw[2 * t] = ex[e0] * inv;
      ti[2 * t + 1] = e1; tw[2 * t + 1] = ex[e1] * inv;
      atomicAdd(&lcnt[e0], 1);
      atomicAdd(&lcnt[e1], 1);
    }
  }
  __syncthreads();
  if (tid < NE) atomicAdd(&cnt[tid], lcnt[tid]);
}

// ---------------- exclusive scan over 8 expert counts ----------------
__global__ void scan_kernel(const int* __restrict__ cnt, int* __restrict__ base,
                            int* __restrict__ cursor) {
  if (threadIdx.x == 0 && blockIdx.x == 0) {
    int r = 0;
    for (int e = 0; e < NE; ++e) { base[e] = r; cursor[e] = r; r += cnt[e]; }
  }
}

// ---------------- scatter (block-aggregated) ----------------
__global__ __launch_bounds__(256) void scatter_kernel(
    const int* __restrict__ ti, int* __restrict__ cursor,
    int* __restrict__ tok, int* __restrict__ dst) {
  __shared__ int lcnt[NE], gbase[NE];
  const int tid = threadIdx.x;
  if (tid < NE) lcnt[tid] = 0;
  __syncthreads();
  const int t = blockIdx.x * 256 + tid;
  const int e0 = ti[2 * t], e1 = ti[2 * t + 1];
  const int p0 = atomicAdd(&lcnt[e0], 1);
  const int p1 = atomicAdd(&lcnt[e1], 1);
  __syncthreads();
  if (tid < NE) gbase[tid] = atomicAdd(&cursor[tid], lcnt[tid]);
  __syncthreads();
  const int i0 = gbase[e0] + p0, i1 = gbase[e1] + p1;
  tok[i0] = t; dst[i0] = 2 * t;
  tok[i1] = t; dst[i1] = 2 * t + 1;
}

// ---------------- gather bf16 x rows into bucket order ----------------
__global__ void gather_kernel(const unsigned short* __restrict__ xb,
                              const int* __restrict__ tok,
                              unsigned short* __restrict__ xg) {
  int i = blockIdx.x * blockDim.x + threadIdx.x;
  int entry = i >> 6, l = i & 63;
  int t = tok[entry];
  ((uint4*)xg)[entry * 64 + l] = ((const uint4*)xb)[t * 64 + l];
}

// =====================================================================
// GEMM tiles: BK=64 (128B rows) with XOR chunk-swizzle (T2, rule-21):
//   LDS layout [R][64] bf16; 16B-chunk c of row r stored at chunk (c ^ (r&7)).
//   global_load_lds dest stays LINEAR; the global SOURCE chunk is pre-swizzled;
//   ds_read applies the same XOR. Residual conflict: 2-way (free, m136).
// =====================================================================

// ---------------- GEMM1: g = silu(A@W1^T) * (A@W3^T), bf16 out ----------------
// Tile 128M x 64N, BK=64, 4 waves (2Mx2N, per-wave 64x32). Dual acc = 64 AGPR.
template <bool ROUTED>
__global__ __launch_bounds__(256, 3) void gemm1_kernel(
    const unsigned short* __restrict__ A0, const unsigned short* __restrict__ W1,
    const unsigned short* __restrict__ W3, unsigned short* __restrict__ G,
    const int* __restrict__ cnt, const int* __restrict__ base,
    int K, int N, int mtPerE) {
  int e, mt, cntE, rowbase;
  if constexpr (ROUTED) {
    e = blockIdx.x / mtPerE; mt = blockIdx.x % mtPerE;
    cntE = cnt[e];
    if (mt * 128 >= cntE) return;
    rowbase = base[e];
  } else {
    e = 0; mt = blockIdx.x; cntE = T_TOK; rowbase = 0;
  }
  const int m0 = mt * 128;
  const int n0 = blockIdx.y * 64;
  const unsigned short* A = A0 + (size_t)rowbase * K;
  const unsigned short* B1 = W1 + (size_t)e * N * K + (size_t)n0 * K;
  const unsigned short* B3 = W3 + (size_t)e * N * K + (size_t)n0 * K;

  __shared__ __align__(16) unsigned short As[128 * 64];
  __shared__ __align__(16) unsigned short B1s[64 * 64];
  __shared__ __align__(16) unsigned short B3s[64 * 64];

  const int tid = threadIdx.x;
  const int w = tid >> 6, lane = tid & 63;
  const int wr = w >> 1, wc = w & 1;
  const int lhi = lane >> 4, llo = lane & 15;

  // staging sources (pre-swizzled global chunk) + linear LDS dests
  const unsigned short* aSrc[4];
  unsigned short* aDst[4];
#pragma unroll
  for (int i = 0; i < 4; ++i) {
    int L = i * 256 + tid, row = L >> 3, c = L & 7, sc = c ^ (row & 7);
    int ar = ROUTED ? min(m0 + row, cntE - 1) : (m0 + row);
    aSrc[i] = A + (size_t)ar * K + sc * 8;
    aDst[i] = &As[(size_t)(i * 256 + (tid & ~63)) * 8];
  }
  const unsigned short *b1Src[2], *b3Src[2];
  unsigned short *b1Dst[2], *b3Dst[2];
#pragma unroll
  for (int i = 0; i < 2; ++i) {
    int L = i * 256 + tid, row = L >> 3, c = L & 7, sc = c ^ (row & 7);
    b1Src[i] = B1 + (size_t)row * K + sc * 8;
    b3Src[i] = B3 + (size_t)row * K + sc * 8;
    b1Dst[i] = &B1s[(size_t)(i * 256 + (tid & ~63)) * 8];
    b3Dst[i] = &B3s[(size_t)(i * 256 + (tid & ~63)) * 8];
  }

  // swizzled ds_read offsets (ushort units)
  int aOff[4][2], bOff[2][2];
#pragma unroll
  for (int m = 0; m < 4; ++m) {
    int r = wr * 64 + m * 16 + llo;
#pragma unroll
    for (int s = 0; s < 2; ++s)
      aOff[m][s] = r * 64 + (((lhi + 4 * s) ^ (r & 7)) * 8);
  }
#pragma unroll
  for (int n = 0; n < 2; ++n) {
    int r = wc * 32 + n * 16 + llo;
#pragma unroll
    for (int s = 0; s < 2; ++s)
      bOff[n][s] = r * 64 + (((lhi + 4 * s) ^ (r & 7)) * 8);
  }

  f32x4 acc1[4][2], acc3[4][2];
#pragma unroll
  for (int m = 0; m < 4; ++m)
#pragma unroll
    for (int n = 0; n < 2; ++n) {
      acc1[m][n] = f32x4{0.f, 0.f, 0.f, 0.f};
      acc3[m][n] = f32x4{0.f, 0.f, 0.f, 0.f};
    }

  for (int k0 = 0; k0 < K; k0 += 64) {
#pragma unroll
    for (int i = 0; i < 4; ++i) async16(aDst[i], aSrc[i] + k0);
#pragma unroll
    for (int i = 0; i < 2; ++i) {
      async16(b1Dst[i], b1Src[i] + k0);
      async16(b3Dst[i], b3Src[i] + k0);
    }
    __syncthreads();
#pragma unroll
    for (int s = 0; s < 2; ++s) {
      s16x8 a[4], b1f[2], b3f[2];
#pragma unroll
      for (int m = 0; m < 4; ++m) a[m] = *(const s16x8*)&As[aOff[m][s]];
#pragma unroll
      for (int n = 0; n < 2; ++n) {
        b1f[n] = *(const s16x8*)&B1s[bOff[n][s]];
        b3f[n] = *(const s16x8*)&B3s[bOff[n][s]];
      }
#pragma unroll
      for (int m = 0; m < 4; ++m)
#pragma unroll
        for (int n = 0; n < 2; ++n) {
          acc1[m][n] = __builtin_amdgcn_mfma_f32_16x16x32_bf16(a[m], b1f[n], acc1[m][n], 0, 0, 0);
          acc3[m][n] = __builtin_amdgcn_mfma_f32_16x16x32_bf16(a[m], b3f[n], acc3[m][n], 0, 0, 0);
        }
    }
    __syncthreads();
  }

  unsigned short* Grow = G + (size_t)rowbase * N;
#pragma unroll
  for (int m = 0; m < 4; ++m)
#pragma unroll
    for (int n = 0; n < 2; ++n)
#pragma unroll
      for (int q = 0; q < 4; ++q) {
        int r = wr * 64 + m * 16 + lhi * 4 + q;
        if (!ROUTED || (m0 + r) < cntE) {
          float h1 = acc1[m][n][q], h3 = acc3[m][n][q];
          float val = (h1 / (1.f + __expf(-h1))) * h3;
          Grow[(size_t)(m0 + r) * N + n0 + wc * 32 + n * 16 + llo] = f2bf(val);
        }
      }
}

// ---------------- GEMM2: out = A@W2^T (fp32, scattered when ROUTED) -----------
// Tile 128M x 128N, BK=64, 4 waves (2x2, per-wave 64x64). acc = 64 AGPR.
template <bool ROUTED>
__global__ __launch_bounds__(256, 3) void gemm2_kernel(
    const unsigned short* __restrict__ A0, const unsigned short* __restrict__ W2,
    float* __restrict__ Out, const int* __restrict__ cnt, const int* __restrict__ base,
    const int* __restrict__ dst, int K, int mtPerE) {
  int e, mt, cntE, rowbase;
  if constexpr (ROUTED) {
    e = blockIdx.x / mtPerE; mt = blockIdx.x % mtPerE;
    cntE = cnt[e];
    if (mt * 128 >= cntE) return;
    rowbase = base[e];
  } else {
    e = 0; mt = blockIdx.x; cntE = T_TOK; rowbase = 0;
  }
  const int m0 = mt * 128;
  const int n0 = blockIdx.y * 128;
  const unsigned short* A = A0 + (size_t)rowbase * K;
  const unsigned short* B = W2 + (size_t)e * DIMSZ * K + (size_t)n0 * K;

  __shared__ __align__(16) unsigned short As[128 * 64];
  __shared__ __align__(16) unsigned short Bs[128 * 64];

  const int tid = threadIdx.x;
  const int w = tid >> 6, lane = tid & 63;
  const int wr = w >> 1, wc = w & 1;
  const int lhi = lane >> 4, llo = lane & 15;

  const unsigned short *aSrc[4], *bSrc[4];
  unsigned short *aDst[4], *bDst[4];
#pragma unroll
  for (int i = 0; i < 4; ++i) {
    int L = i * 256 + tid, row = L >> 3, c = L & 7, sc = c ^ (row & 7);
    int ar = ROUTED ? min(m0 + row, cntE - 1) : (m0 + row);
    aSrc[i] = A + (size_t)ar * K + sc * 8;
    bSrc[i] = B + (size_t)row * K + sc * 8;
    aDst[i] = &As[(size_t)(i * 256 + (tid & ~63)) * 8];
    bDst[i] = &Bs[(size_t)(i * 256 + (tid & ~63)) * 8];
  }

  int aOff[4][2], bOff[4][2];
#pragma unroll
  for (int m = 0; m < 4; ++m) {
    int ra = wr * 64 + m * 16 + llo;
    int rb = wc * 64 + m * 16 + llo;
#pragma unroll
    for (int s = 0; s < 2; ++s) {
      aOff[m][s] = ra * 64 + (((lhi + 4 * s) ^ (ra & 7)) * 8);
      bOff[m][s] = rb * 64 + (((lhi + 4 * s) ^ (rb & 7)) * 8);
    }
  }

  f32x4 acc[4][4];
#pragma unroll
  for (int i = 0; i < 4; ++i)
#pragma unroll
    for (int j = 0; j < 4; ++j) acc[i][j] = f32x4{0.f, 0.f, 0.f, 0.f};

  for (int k0 = 0; k0 < K; k0 += 64) {
#pragma unroll
    for (int i = 0; i < 4; ++i) {
      async16(aDst[i], aSrc[i] + k0);
      async16(bDst[i], bSrc[i] + k0);
    }
    __syncthreads();
#pragma unroll
    for (int s = 0; s < 2; ++s) {
      s16x8 a[4], b[4];
#pragma unroll
      for (int m = 0; m < 4; ++m) {
        a[m] = *(const s16x8*)&As[aOff[m][s]];
        b[m] = *(const s16x8*)&Bs[bOff[m][s]];
      }
#pragma unroll
      for (int i = 0; i < 4; ++i)
#pragma unroll
        for (int j = 0; j < 4; ++j)
          acc[i][j] = __builtin_amdgcn_mfma_f32_16x16x32_bf16(a[i], b[j], acc[i][j], 0, 0, 0);
    }
    __syncthreads();
  }

#pragma unroll
  for (int i = 0; i < 4; ++i)
#pragma unroll
    for (int j = 0; j < 4; ++j)
#pragma unroll
      for (int q = 0; q < 4; ++q) {
        int r = wr * 64 + i * 16 + lhi * 4 + q;
        if (!ROUTED || (m0 + r) < cntE) {
          int orow;
          if constexpr (ROUTED) orow = dst[rowbase + m0 + r];
          else                  orow = m0 + r;
          Out[(size_t)orow * DIMSZ + n0 + wc * 64 + j * 16 + llo] = acc[i][j][q];
        }
      }
}

// ---------------- final combine: out = shared + w0*p0 + w1*p1 ----------------
__global__ void combine_kernel(const float* __restrict__ shbuf, const float* __restrict__ pair,
                               const float* __restrict__ tw, float* __restrict__ out) {
  int i = blockIdx.x * blockDim.x + threadIdx.x;
  int t = i >> 7, c = i & 127;
  float w0 = tw[2 * t], w1 = tw[2 * t + 1];
  float4 a = ((const float4*)shbuf)[i];
  float4 p0 = ((const float4*)pair)[(size_t)(2 * t) * 128 + c];
  float4 p1 = ((const float4*)pair)[(size_t)(2 * t + 1) * 128 + c];
  float4 o;
  o.x = a.x + w0 * p0.x + w1 * p1.x;
  o.y = a.y + w0 * p0.y + w1 * p1.y;
  o.z = a.z + w0 * p0.z + w1 * p1.z;
  o.w = a.w + w0 * p0.w + w1 * p1.w;
  ((float4*)out)[i] = o;
}

extern "C" void kernel_launch(void* const* d_in, const int* in_sizes, int n_in,
                              void* d_out, int out_size, void* d_ws, size_t ws_size,
                              hipStream_t stream) {
  const float* x   = (const float*)d_in[0];
  const float* gw  = (const float*)d_in[1];
  const float* w1  = (const float*)d_in[2];
  const float* w3  = (const float*)d_in[3];
  const float* w2  = (const float*)d_in[4];
  const float* sw1 = (const float*)d_in[5];
  const float* sw3 = (const float*)d_in[6];
  const float* sw2 = (const float*)d_in[7];
  float* out = (float*)d_out;

  char* p = (char*)d_ws;
  auto alloc = [&](size_t bytes) {
    char* r = p;
    p += (bytes + 255) & ~(size_t)255;
    return r;
  };
  unsigned short* xb   = (unsigned short*)alloc((size_t)T_TOK * DIMSZ * 2);
  unsigned short* xg   = (unsigned short*)alloc((size_t)2 * T_TOK * DIMSZ * 2);
  unsigned short* w1b  = (unsigned short*)alloc((size_t)NE * HIDSZ * DIMSZ * 2);
  unsigned short* w3b  = (unsigned short*)alloc((size_t)NE * HIDSZ * DIMSZ * 2);
  unsigned short* w2b  = (unsigned short*)alloc((size_t)NE * DIMSZ * HIDSZ * 2);
  unsigned short* sw1b = (unsigned short*)alloc((size_t)SHIDSZ * DIMSZ * 2);
  unsigned short* sw3b = (unsigned short*)alloc((size_t)SHIDSZ * DIMSZ * 2);
  unsigned short* sw2b = (unsigned short*)alloc((size_t)DIMSZ * SHIDSZ * 2);
  unsigned short* g    = (unsigned short*)alloc((size_t)T_TOK * SHIDSZ * 2);
  float* pairout = (float*)alloc((size_t)2 * T_TOK * DIMSZ * 4);
  float* shbuf   = (float*)alloc((size_t)T_TOK * DIMSZ * 4);
  float* tw = (float*)alloc((size_t)2 * T_TOK * 4);
  int* ti   = (int*)alloc((size_t)2 * T_TOK * 4);
  int* tok  = (int*)alloc((size_t)2 * T_TOK * 4);
  int* dst  = (int*)alloc((size_t)2 * T_TOK * 4);
  int* meta = (int*)alloc(256);
  int* cnt = meta, *cursor = meta + 8, *base = meta + 16;

  auto cvt = [&](const float* s, unsigned short* d, size_t n) {
    int n4 = (int)(n / 4);
    cvt_bf16<<<(n4 + 255) / 256, 256, 0, stream>>>(s, d, n4);
  };
  cvt(x, xb, (size_t)T_TOK * DIMSZ);
  cvt(w1, w1b, (size_t)NE * HIDSZ * DIMSZ);
  cvt(w3, w3b, (size_t)NE * HIDSZ * DIMSZ);
  cvt(w2, w2b, (size_t)NE * DIMSZ * HIDSZ);
  cvt(sw1, sw1b, (size_t)SHIDSZ * DIMSZ);
  cvt(sw3, sw3b, (size_t)SHIDSZ * DIMSZ);
  cvt(sw2, sw2b, (size_t)DIMSZ * SHIDSZ);

  hipMemsetAsync(meta, 0, 64, stream);
  gate_kernel<<<GATE_BLOCKS, 256, 0, stream>>>(x, gw, tw, ti, cnt);
  scan_kernel<<<1, 64, 0, stream>>>(cnt, base, cursor);
  scatter_kernel<<<T_TOK / 256, 256, 0, stream>>>(ti, cursor, tok, dst);
  gather_kernel<<<(2 * T_TOK * 64) / 256, 256, 0, stream>>>(xb, tok, xg);

  // shared expert (dense) — g as [8192, 3072]
  gemm1_kernel<false><<<dim3(T_TOK / 128, SHIDSZ / 64), 256, 0, stream>>>(
      xb, sw1b, sw3b, g, nullptr, nullptr, DIMSZ, SHIDSZ, T_TOK / 128);
  gemm2_kernel<false><<<dim3(T_TOK / 128, DIMSZ / 128), 256, 0, stream>>>(
      g, sw2b, shbuf, nullptr, nullptr, nullptr, SHIDSZ, T_TOK / 128);

  // routed experts — g reused as [16384, 1536]
  gemm1_kernel<true><<<dim3(NE * (T_TOK / 128), HIDSZ / 64), 256, 0, stream>>>(
      xg, w1b, w3b, g, cnt, base, DIMSZ, HIDSZ, T_TOK / 128);
  gemm2_kernel<true><<<dim3(NE * (T_TOK / 128), DIMSZ / 128), 256, 0, stream>>>(
      g, w2b, pairout, cnt, base, dst, HIDSZ, T_TOK / 128);

  combine_kernel<<<(T_TOK * 128) / 256, 256, 0, stream>>>(shbuf, pairout, tw, out);
}